// Round 1
// baseline (89.500 us; speedup 1.0000x reference)
//
#include <hip/hip_runtime.h>

#define EPS 1e-7f
#define TILE_H 16
#define RY 4
#define LDS_ROWS 22   // TILE_H + 6
#define LDS_COLS 64

// mantissa_map: (|v|+eps) scaled to [1,2) mantissa m; result = m>=1.5 ? m/2 : m  -> [0.75,1.5)
__device__ __forceinline__ float mant_map(float v) {
    float a = fabsf(v) + EPS;
    unsigned int bi = __float_as_uint(a);
    float m = __uint_as_float((bi & 0x007FFFFFu) | 0x3F800000u); // mantissa in [1,2)
    return (m >= 1.5f) ? 0.5f * m : m;
}

__global__ __launch_bounds__(256) void wconv_kernel(const float* __restrict__ x,
                                                    const float* __restrict__ w,
                                                    float* __restrict__ out) {
    __shared__ float2 sp[LDS_ROWS][LDS_COLS];  // {u = x, v = x/M1}
    __shared__ float2 swt[49];                 // {B = w/M2, C = B*(M2-1)}

    const int tx = threadIdx.x;      // 0..63 (output col; active if <56)
    const int ty = threadIdx.y;      // 0..3
    const int tid = ty * 64 + tx;    // 0..255
    const int tile = blockIdx.x;     // 0..3   (y tiles of 16)
    const int c = blockIdx.y;        // 0..191
    const int b = blockIdx.z;        // 0..3

    const int y0 = tile * TILE_H;
    const long plane = (long)(b * 192 + c) * (56 * 56);
    const float* xp = x + plane;

    // --- weights: per-tap constants ---
    if (tid < 49) {
        float wv = w[c * 49 + tid];
        float M2 = mant_map(wv);
        float B = wv / M2;
        swt[tid] = make_float2(B, B * (M2 - 1.0f));
    }

    // --- stage input halo tile: input rows y0-3 .. y0+18, cols -3 .. 60 ---
    for (int idx = tid; idx < LDS_ROWS * LDS_COLS; idx += 256) {
        int r  = idx >> 6;
        int lc = idx & 63;
        int ir = y0 - 3 + r;
        int ic = lc - 3;
        float u = 0.0f;
        if (ir >= 0 && ir < 56 && ic >= 0 && ic < 56)
            u = xp[ir * 56 + ic];
        float v = u / mant_map(u);   // u==0 (padding or exact zero) -> v=0, contributes 0
        sp[r][lc] = make_float2(u, v);
    }
    __syncthreads();

    if (tx < 56) {
        float acc[RY] = {0.f, 0.f, 0.f, 0.f};
        const int rb = ty * RY;  // top output row within tile

        #pragma unroll
        for (int i = 0; i < 7; ++i) {
            #pragma unroll
            for (int j = 0; j < 7; ++j) {
                float2 wc = swt[i * 7 + j];
                #pragma unroll
                for (int ry = 0; ry < RY; ++ry) {
                    float2 p = sp[rb + ry + i][tx + j];
                    acc[ry] = fmaf(p.x, wc.x, fmaf(p.y, wc.y, acc[ry]));
                }
            }
        }

        #pragma unroll
        for (int ry = 0; ry < RY; ++ry) {
            int y = y0 + rb + ry;
            if (y < 56)
                out[plane + y * 56 + tx] = acc[ry];
        }
    }
}

extern "C" void kernel_launch(void* const* d_in, const int* in_sizes, int n_in,
                              void* d_out, int out_size, void* d_ws, size_t ws_size,
                              hipStream_t stream) {
    const float* x = (const float*)d_in[0];   // (4,192,56,56) fp32
    const float* w = (const float*)d_in[1];   // (192,1,7,7) fp32
    float* out = (float*)d_out;               // (4,192,56,56) fp32

    dim3 grid(4, 192, 4);   // (y-tiles, C, B)
    dim3 block(64, 4);
    hipLaunchKernelGGL(wconv_kernel, grid, block, 0, stream, x, w, out);
}

// Round 2
// 72.560 us; speedup vs baseline: 1.2335x; 1.2335x over previous
//
#include <hip/hip_runtime.h>

typedef float v2f __attribute__((ext_vector_type(2)));

#define EPS 1e-7f
#define TILE_H 14
#define RY 7
#define LDS_ROWS 20   // TILE_H + 6
#define LDS_COLS 64

// mantissa_map: (|v|+eps) -> mantissa m in [1,2); result = m>=1.5 ? m/2 : m  -> [0.75,1.5)
__device__ __forceinline__ float mant_map(float v) {
    float a = fabsf(v) + EPS;
    unsigned int bi = __float_as_uint(a);
    float m = __uint_as_float((bi & 0x007FFFFFu) | 0x3F800000u);
    return (m >= 1.5f) ? 0.5f * m : m;
}

// Pre-kernel: per-channel tap constants {B = w/M2, C = B*(M2-1)} into workspace.
__global__ __launch_bounds__(64) void wprep_kernel(const float* __restrict__ w,
                                                   v2f* __restrict__ wt) {
    int t = blockIdx.x * 64 + threadIdx.x;
    if (t < 192 * 49) {
        float wv = w[t];
        float M2 = mant_map(wv);
        float B = wv / M2;                 // exact divide, tiny kernel
        wt[t] = (v2f){B, B * (M2 - 1.0f)};
    }
}

__global__ __launch_bounds__(128) void wconv_kernel(const float* __restrict__ x,
                                                    const v2f* __restrict__ wtab,
                                                    float* __restrict__ out) {
    __shared__ v2f sp[LDS_ROWS][LDS_COLS];  // {u = x, v = x/M1}

    const int tx = threadIdx.x;       // 0..63 (output col; active if <56)
    const int ty = threadIdx.y;       // 0..1
    const int tid = ty * 64 + tx;
    const int tile = blockIdx.x;      // 0..3 (y tiles of 14; 4*14 = 56 exact)
    const int c = blockIdx.y;
    const int b = blockIdx.z;

    const int y0 = tile * TILE_H;
    const long plane = (long)(b * 192 + c) * (56 * 56);
    const float* xp = x + plane;
    const v2f* wt = wtab + c * 49;    // uniform -> s_load

    // --- stage halo tile: input rows y0-3 .. y0+16, cols -3..60 ---
    for (int idx = tid; idx < LDS_ROWS * LDS_COLS; idx += 128) {
        int r = idx >> 6, lc = idx & 63;
        int ir = y0 - 3 + r, ic = lc - 3;
        float u = 0.0f;
        if (ir >= 0 && ir < 56 && ic >= 0 && ic < 56)
            u = xp[ir * 56 + ic];
        float v = u * __builtin_amdgcn_rcpf(mant_map(u));  // u==0 -> v==0 (pad contributes 0)
        sp[r][lc] = (v2f){u, v};
    }
    __syncthreads();

    if (tx < 56) {
        v2f acc[RY];
        #pragma unroll
        for (int r = 0; r < RY; ++r) acc[r] = (v2f){0.f, 0.f};
        const int rb = ty * RY;       // top output row within tile

        // Slide over the 13 input rows this thread needs; each LDS pixel read ONCE.
        #pragma unroll
        for (int ir = 0; ir < RY + 6; ++ir) {
            v2f p[7];
            #pragma unroll
            for (int j = 0; j < 7; ++j) p[j] = sp[rb + ir][tx + j];
            #pragma unroll
            for (int ry = 0; ry < RY; ++ry) {
                // weight row i = ir - ry must be in [0,6]; resolves at compile time
                if (ir - ry >= 0 && ir - ry <= 6) {
                    const v2f* wr = wt + (ir - ry) * 7;
                    #pragma unroll
                    for (int j = 0; j < 7; ++j)
                        acc[ry] += p[j] * wr[j];   // v_pk_fma_f32, weights from SGPRs
                }
            }
        }

        #pragma unroll
        for (int ry = 0; ry < RY; ++ry)
            out[plane + (y0 + rb + ry) * 56 + tx] = acc[ry].x + acc[ry].y;
    }
}

extern "C" void kernel_launch(void* const* d_in, const int* in_sizes, int n_in,
                              void* d_out, int out_size, void* d_ws, size_t ws_size,
                              hipStream_t stream) {
    const float* x = (const float*)d_in[0];   // (4,192,56,56) fp32
    const float* w = (const float*)d_in[1];   // (192,1,7,7) fp32
    float* out = (float*)d_out;
    v2f* wt = (v2f*)d_ws;                     // 192*49 float2 = 75 KB

    hipLaunchKernelGGL(wprep_kernel, dim3(147), dim3(64), 0, stream, w, wt);
    hipLaunchKernelGGL(wconv_kernel, dim3(4, 192, 4), dim3(64, 2), 0, stream, x, wt, out);
}